// Round 6
// baseline (395.841 us; speedup 1.0000x reference)
//
#include <hip/hip_runtime.h>

typedef __bf16 bf16x8 __attribute__((ext_vector_type(8)));
typedef float  f32x4  __attribute__((ext_vector_type(4)));

#define TSEQ 2048
#define CDIM 1024
#define NHEAD 16
#define DH 64

__device__ __forceinline__ void gl_lds16(const void* g, void* l) {
  __builtin_amdgcn_global_load_lds(
      (const __attribute__((address_space(1))) unsigned int*)g,
      (__attribute__((address_space(3))) unsigned int*)l, 16, 0, 0);
}

template <int PAT>
__device__ __forceinline__ float swz(float x) {
  return __int_as_float(__builtin_amdgcn_ds_swizzle(__float_as_int(x), PAT));
}

__device__ __forceinline__ float fexp2(float x) { return __builtin_amdgcn_exp2f(x); }

// ---------------- fp32 -> bf16 conversion (vectorized) ----------------
__global__ __launch_bounds__(256) void cvt_bf16(const float* __restrict__ in,
                                                __bf16* __restrict__ out, int n8) {
  int i = blockIdx.x * 256 + threadIdx.x;
  if (i >= n8) return;
  const float4* p = (const float4*)(in + (size_t)i * 8);
  float4 a = p[0], b = p[1];
  bf16x8 r;
  r[0] = (__bf16)a.x; r[1] = (__bf16)a.y; r[2] = (__bf16)a.z; r[3] = (__bf16)a.w;
  r[4] = (__bf16)b.x; r[5] = (__bf16)b.y; r[6] = (__bf16)b.z; r[7] = (__bf16)b.w;
  *(bf16x8*)(out + (size_t)i * 8) = r;
}

// ---------------- bf16 GEMM (m97-style): out[M,N] = A[M,K]*Bw[N,K]^T + bias --------
template <int EPI>
__global__ __launch_bounds__(256) void gemm_bt(
    const __bf16* __restrict__ A, const __bf16* __restrict__ Bw,
    const float* __restrict__ bias, float* __restrict__ outf,
    __bf16* __restrict__ q_buf, __bf16* __restrict__ k_buf,
    __bf16* __restrict__ vT_buf, int M, int N, int K) {
  __shared__ alignas(16) __bf16 lda[128 * 64];
  __shared__ alignas(16) __bf16 ldb[128 * 64];
  const int tid = threadIdx.x;
  const int lane = tid & 63, wid = tid >> 6;
  const int wm = wid >> 1, wn = wid & 1;
  const int row0 = blockIdx.y * 128, col0 = blockIdx.x * 128;
  f32x4 acc[4][4] = {};

  const int srow = lane >> 3;
  const int scb = (lane & 7) * 16;

  for (int k0 = 0; k0 < K; k0 += 64) {
#pragma unroll
    for (int j = 0; j < 4; ++j) {
      int blk = j * 4 + wid;
      int r = blk * 8 + srow;
      char* la = (char*)lda + blk * 1024;
      char* lb = (char*)ldb + blk * 1024;
      gl_lds16((const char*)(A + (size_t)(row0 + r) * K + k0) + scb, la);
      gl_lds16((const char*)(Bw + (size_t)(col0 + r) * K + k0) + scb, lb);
    }
    __syncthreads();
#pragma unroll
    for (int kk = 0; kk < 2; ++kk) {
      bf16x8 af[4], bfr[4];
#pragma unroll
      for (int m = 0; m < 4; ++m)
        af[m] = *(const bf16x8*)&lda[(wm * 64 + m * 16 + (lane & 15)) * 64 + kk * 32 + (lane >> 4) * 8];
#pragma unroll
      for (int n = 0; n < 4; ++n)
        bfr[n] = *(const bf16x8*)&ldb[(wn * 64 + n * 16 + (lane & 15)) * 64 + kk * 32 + (lane >> 4) * 8];
#pragma unroll
      for (int m = 0; m < 4; ++m)
#pragma unroll
        for (int n = 0; n < 4; ++n)
          acc[m][n] = __builtin_amdgcn_mfma_f32_16x16x32_bf16(af[m], bfr[n], acc[m][n], 0, 0, 0);
    }
    __syncthreads();
  }
#pragma unroll
  for (int m = 0; m < 4; ++m) {
#pragma unroll
    for (int n = 0; n < 4; ++n) {
#pragma unroll
      for (int i = 0; i < 4; ++i) {
        int r = row0 + wm * 64 + m * 16 + (lane >> 4) * 4 + i;
        int c = col0 + wn * 64 + n * 16 + (lane & 15);
        float v = acc[m][n][i] + bias[c];
        if (EPI == 0) {
          outf[(size_t)r * N + c] = v;
        } else {
          int bb = r >> 11, t = r & 2047;
          int sec = c >> 10, cc = c & 1023;
          int hh = cc >> 6, d = cc & 63;
          size_t bh = (size_t)bb * NHEAD + hh;
          __bf16 bv = (__bf16)v;
          if (sec == 0)      q_buf[(bh * TSEQ + (size_t)t) * DH + d] = bv;
          else if (sec == 1) k_buf[(bh * TSEQ + (size_t)t) * DH + d] = bv;
          else               vT_buf[(bh * DH + (size_t)d) * TSEQ + t] = bv;
        }
      }
    }
  }
}

// ---------------- flash attention: heavy+light pairs, 4 pairs per block ----------------
// Block = 256 thr = 4 waves, all same bh; wave w owns pair {wv, 127-wv}, wv=4*y+w.
// Pairs are uniform in total work; pairs within a block differ by <=1 iter -> uniform
// block lifetime -> 512 balanced blocks. No barriers (per-wave LDS regions).
// grid (bh=32, y=16): linear id % 8 == bh % 8 -> XCD-local K/V (4 heads, 2MB, L2-fit).
__device__ __forceinline__ void qk_softmax_p(
    int kt, int qrow0, int lane, float scale2, float slope2,
    const bf16x8* qf, const bf16x8 (*kf)[2],
    f32x4* o, float* mrow, float* lrow, __bf16 (*p)[68]) {
  f32x4 s[4];
#pragma unroll
  for (int n = 0; n < 4; ++n) {
    f32x4 z = {};
    z = __builtin_amdgcn_mfma_f32_16x16x32_bf16(qf[0], kf[n][0], z, 0, 0, 0);
    s[n] = __builtin_amdgcn_mfma_f32_16x16x32_bf16(qf[1], kf[n][1], z, 0, 0, 0);
  }
  const int qr0 = qrow0 + (lane >> 4) * 4;
  float sv[4][4];
  float tmax[4] = {-__builtin_inff(), -__builtin_inff(), -__builtin_inff(), -__builtin_inff()};
#pragma unroll
  for (int n = 0; n < 4; ++n) {
    int kc = kt + n * 16 + (lane & 15);
#pragma unroll
    for (int i = 0; i < 4; ++i) {
      int r = qr0 + i;
      float x = (kc <= r) ? (s[n][i] * scale2 + slope2 * (float)(kc - r)) : -__builtin_inff();
      sv[n][i] = x;
      tmax[i] = fmaxf(tmax[i], x);
    }
  }
#pragma unroll
  for (int i = 0; i < 4; ++i) {
    float t = tmax[i];
    t = fmaxf(t, swz<0x041F>(t));
    t = fmaxf(t, swz<0x081F>(t));
    t = fmaxf(t, swz<0x101F>(t));
    t = fmaxf(t, swz<0x201F>(t));
    float mnew = fmaxf(mrow[i], t);
    float corr = fexp2(mrow[i] - mnew);
    mrow[i] = mnew;
    float rs = 0.f;
    float pf[4];
#pragma unroll
    for (int n = 0; n < 4; ++n) {
      pf[n] = fexp2(sv[n][i] - mnew);
      rs += pf[n];
    }
    rs += swz<0x041F>(rs);
    rs += swz<0x081F>(rs);
    rs += swz<0x101F>(rs);
    rs += swz<0x201F>(rs);
    lrow[i] = lrow[i] * corr + rs;
#pragma unroll
    for (int n2 = 0; n2 < 4; ++n2) o[n2][i] *= corr;
#pragma unroll
    for (int n = 0; n < 4; ++n)
      p[(lane >> 4) * 4 + i][n * 16 + (lane & 15)] = (__bf16)pf[n];
  }
}

__device__ __forceinline__ void pv_acc(
    int lane, const bf16x8 (*vf)[2], f32x4* o, const __bf16 (*p)[68]) {
  bf16x8 pa[2];
#pragma unroll
  for (int kk = 0; kk < 2; ++kk)
    pa[kk] = *(const bf16x8*)&p[lane & 15][kk * 32 + (lane >> 4) * 8];
#pragma unroll
  for (int n2 = 0; n2 < 4; ++n2) {
    o[n2] = __builtin_amdgcn_mfma_f32_16x16x32_bf16(pa[0], vf[n2][0], o[n2], 0, 0, 0);
    o[n2] = __builtin_amdgcn_mfma_f32_16x16x32_bf16(pa[1], vf[n2][1], o[n2], 0, 0, 0);
  }
}

__global__ __launch_bounds__(256, 4) void attn_fwd(
    const __bf16* __restrict__ q_buf, const __bf16* __restrict__ k_buf,
    const __bf16* __restrict__ vT_buf, __bf16* __restrict__ y_buf) {
  const int T = TSEQ;
  const int tid = threadIdx.x;
  const int lane = tid & 63, wid = tid >> 6;
  const int bh = blockIdx.x;
  const int wv = blockIdx.y * 4 + wid;
  const int b = bh >> 4, h = bh & 15;
  const int row0[2] = {(127 - wv) * 16, wv * 16};  // 0=heavy, 1=light
  const float scale2 = 0.125f * 1.44269504f;
  const float slope2 = exp2f(-0.5f * (float)(h + 1)) * 1.44269504f;
  const __bf16* qp = q_buf + (size_t)bh * T * DH;
  const __bf16* kp = k_buf + (size_t)bh * T * DH;
  const __bf16* vp = vT_buf + (size_t)bh * DH * T;

  // per-wave P regions; row stride 68 elems -> conflict-free P writes (R5-verified)
  __shared__ alignas(16) __bf16 p_lds[4][2][16][68];

  bf16x8 qf[2][2];
#pragma unroll
  for (int g = 0; g < 2; ++g) {
    const __bf16* qr = &qp[(size_t)(row0[g] + (lane & 15)) * DH + (lane >> 4) * 8];
#pragma unroll
    for (int kk = 0; kk < 2; ++kk) qf[g][kk] = *(const bf16x8*)(qr + kk * 32);
  }

  f32x4 o[2][4] = {};
  float mrow[2][4], lrow[2][4];
#pragma unroll
  for (int g = 0; g < 2; ++g)
#pragma unroll
    for (int i = 0; i < 4; ++i) { mrow[g][i] = -__builtin_inff(); lrow[g][i] = 0.f; }

  const int klo = (lane & 15) * DH + (lane >> 4) * 8;
  const int vlo = (lane & 15) * T + (lane >> 4) * 8;
  const int hend = row0[0] + 15;  // heavy group governs loop & loads
  const int lend = row0[1] + 15;

  bf16x8 kf[4][2];
#pragma unroll
  for (int n = 0; n < 4; ++n) {
    const __bf16* kr = kp + n * 16 * DH + klo;
    kf[n][0] = *(const bf16x8*)kr;
    kf[n][1] = *(const bf16x8*)(kr + 32);
  }

  for (int kt = 0; kt <= hend; kt += 64) {
    bf16x8 vf[4][2];
#pragma unroll
    for (int n2 = 0; n2 < 4; ++n2) {
      const __bf16* vr = vp + vlo + n2 * 16 * T + kt;
      vf[n2][0] = *(const bf16x8*)vr;
      vf[n2][1] = *(const bf16x8*)(vr + 32);
    }
    bf16x8 kn[4][2];
    if (kt + 64 <= hend) {
#pragma unroll
      for (int n = 0; n < 4; ++n) {
        const __bf16* kr = kp + (size_t)(kt + 64 + n * 16) * DH + klo;
        kn[n][0] = *(const bf16x8*)kr;
        kn[n][1] = *(const bf16x8*)(kr + 32);
      }
    }
    const bool lact = (kt <= lend);
    qk_softmax_p(kt, row0[0], lane, scale2, slope2, qf[0], kf,
                 o[0], mrow[0], lrow[0], p_lds[wid][0]);
    if (lact)
      qk_softmax_p(kt, row0[1], lane, scale2, slope2, qf[1], kf,
                   o[1], mrow[1], lrow[1], p_lds[wid][1]);
    pv_acc(lane, vf, o[0], p_lds[wid][0]);
    if (lact) pv_acc(lane, vf, o[1], p_lds[wid][1]);
#pragma unroll
    for (int n = 0; n < 4; ++n) {
      kf[n][0] = kn[n][0];
      kf[n][1] = kn[n][1];
    }
  }
#pragma unroll
  for (int g = 0; g < 2; ++g) {
#pragma unroll
    for (int i = 0; i < 4; ++i) {
      float inv = 1.0f / lrow[g][i];
      int t = row0[g] + (lane >> 4) * 4 + i;
#pragma unroll
      for (int n2 = 0; n2 < 4; ++n2) {
        int d = n2 * 16 + (lane & 15);
        y_buf[((size_t)b * T + t) * CDIM + h * DH + d] = (__bf16)(o[g][n2][i] * inv);
      }
    }
  }
}

extern "C" void kernel_launch(void* const* d_in, const int* in_sizes, int n_in,
                              void* d_out, int out_size, void* d_ws, size_t ws_size,
                              hipStream_t stream) {
  const float* x      = (const float*)d_in[0];
  const float* W_attn = (const float*)d_in[1];
  const float* b_attn = (const float*)d_in[2];
  const float* W_proj = (const float*)d_in[3];
  const float* b_proj = (const float*)d_in[4];
  float* out = (float*)d_out;
  char* ws = (char*)d_ws;
  const size_t MB = (size_t)1 << 20;
  __bf16* xb  = (__bf16*)(ws + 0 * MB);
  __bf16* wab = (__bf16*)(ws + 8 * MB);
  __bf16* wpb = (__bf16*)(ws + 14 * MB);
  __bf16* qbf = (__bf16*)(ws + 16 * MB);
  __bf16* kbf = (__bf16*)(ws + 24 * MB);
  __bf16* vtb = (__bf16*)(ws + 32 * MB);
  __bf16* yb  = (__bf16*)(ws + 40 * MB);

  cvt_bf16<<<2048, 256, 0, stream>>>(x, xb, 524288);
  cvt_bf16<<<1536, 256, 0, stream>>>(W_attn, wab, 393216);
  cvt_bf16<<<512, 256, 0, stream>>>(W_proj, wpb, 131072);

  gemm_bt<1><<<dim3(24, 32), 256, 0, stream>>>(xb, wab, b_attn, nullptr,
                                               qbf, kbf, vtb, 4096, 3072, 1024);
  attn_fwd<<<dim3(32, 16), 256, 0, stream>>>(qbf, kbf, vtb, yb);
  gemm_bt<0><<<dim3(8, 32), 256, 0, stream>>>(yb, wpb, b_proj, out,
                                              nullptr, nullptr, nullptr, 4096, 1024, 1024);
}

// Round 7
// 207.384 us; speedup vs baseline: 1.9087x; 1.9087x over previous
//
#include <hip/hip_runtime.h>

typedef __bf16 bf16x8 __attribute__((ext_vector_type(8)));
typedef float  f32x4  __attribute__((ext_vector_type(4)));

#define TSEQ 2048
#define CDIM 1024
#define NHEAD 16
#define DH 64
#define SCALE2 0.1803368801111137f  // 0.125 * log2(e)

__device__ __forceinline__ void gl_lds16(const void* g, void* l) {
  __builtin_amdgcn_global_load_lds(
      (const __attribute__((address_space(1))) unsigned int*)g,
      (__attribute__((address_space(3))) unsigned int*)l, 16, 0, 0);
}

__device__ __forceinline__ float fexp2(float x) { return __builtin_amdgcn_exp2f(x); }

// DPP cross-lane (VALU pipe, no LDS latency). Reduce over each 16-lane row.
template <int CTRL>
__device__ __forceinline__ float dppmov(float x) {
  return __int_as_float(__builtin_amdgcn_update_dpp(
      0, __float_as_int(x), CTRL, 0xF, 0xF, true));
}
__device__ __forceinline__ float redmax16(float x) {
  x = fmaxf(x, dppmov<0xB1>(x));   // quad_perm [1,0,3,2] (xor1)
  x = fmaxf(x, dppmov<0x4E>(x));   // quad_perm [2,3,0,1] (xor2)
  x = fmaxf(x, dppmov<0x124>(x));  // row_ror:4
  x = fmaxf(x, dppmov<0x128>(x));  // row_ror:8
  return x;
}
__device__ __forceinline__ float redsum16(float x) {
  x += dppmov<0xB1>(x);
  x += dppmov<0x4E>(x);
  x += dppmov<0x124>(x);
  x += dppmov<0x128>(x);
  return x;
}

// ---------------- fp32 -> bf16 conversion (vectorized) ----------------
__global__ __launch_bounds__(256) void cvt_bf16(const float* __restrict__ in,
                                                __bf16* __restrict__ out, int n8) {
  int i = blockIdx.x * 256 + threadIdx.x;
  if (i >= n8) return;
  const float4* p = (const float4*)(in + (size_t)i * 8);
  float4 a = p[0], b = p[1];
  bf16x8 r;
  r[0] = (__bf16)a.x; r[1] = (__bf16)a.y; r[2] = (__bf16)a.z; r[3] = (__bf16)a.w;
  r[4] = (__bf16)b.x; r[5] = (__bf16)b.y; r[6] = (__bf16)b.z; r[7] = (__bf16)b.w;
  *(bf16x8*)(out + (size_t)i * 8) = r;
}

// ---------------- bf16 GEMM (m97-style): out[M,N] = A[M,K]*Bw[N,K]^T + bias --------
// EPI=1 scatters qkv; q is PRE-SCALED by 0.125*log2e.
template <int EPI>
__global__ __launch_bounds__(256) void gemm_bt(
    const __bf16* __restrict__ A, const __bf16* __restrict__ Bw,
    const float* __restrict__ bias, float* __restrict__ outf,
    __bf16* __restrict__ q_buf, __bf16* __restrict__ k_buf,
    __bf16* __restrict__ vT_buf, int M, int N, int K) {
  __shared__ alignas(16) __bf16 lda[128 * 64];
  __shared__ alignas(16) __bf16 ldb[128 * 64];
  const int tid = threadIdx.x;
  const int lane = tid & 63, wid = tid >> 6;
  const int wm = wid >> 1, wn = wid & 1;
  const int row0 = blockIdx.y * 128, col0 = blockIdx.x * 128;
  f32x4 acc[4][4] = {};

  const int srow = lane >> 3;
  const int scb = (lane & 7) * 16;

  for (int k0 = 0; k0 < K; k0 += 64) {
#pragma unroll
    for (int j = 0; j < 4; ++j) {
      int blk = j * 4 + wid;
      int r = blk * 8 + srow;
      char* la = (char*)lda + blk * 1024;
      char* lb = (char*)ldb + blk * 1024;
      gl_lds16((const char*)(A + (size_t)(row0 + r) * K + k0) + scb, la);
      gl_lds16((const char*)(Bw + (size_t)(col0 + r) * K + k0) + scb, lb);
    }
    __syncthreads();
#pragma unroll
    for (int kk = 0; kk < 2; ++kk) {
      bf16x8 af[4], bfr[4];
#pragma unroll
      for (int m = 0; m < 4; ++m)
        af[m] = *(const bf16x8*)&lda[(wm * 64 + m * 16 + (lane & 15)) * 64 + kk * 32 + (lane >> 4) * 8];
#pragma unroll
      for (int n = 0; n < 4; ++n)
        bfr[n] = *(const bf16x8*)&ldb[(wn * 64 + n * 16 + (lane & 15)) * 64 + kk * 32 + (lane >> 4) * 8];
#pragma unroll
      for (int m = 0; m < 4; ++m)
#pragma unroll
        for (int n = 0; n < 4; ++n)
          acc[m][n] = __builtin_amdgcn_mfma_f32_16x16x32_bf16(af[m], bfr[n], acc[m][n], 0, 0, 0);
    }
    __syncthreads();
  }
#pragma unroll
  for (int m = 0; m < 4; ++m) {
#pragma unroll
    for (int n = 0; n < 4; ++n) {
#pragma unroll
      for (int i = 0; i < 4; ++i) {
        int r = row0 + wm * 64 + m * 16 + (lane >> 4) * 4 + i;
        int c = col0 + wn * 64 + n * 16 + (lane & 15);
        float v = acc[m][n][i] + bias[c];
        if (EPI == 0) {
          outf[(size_t)r * N + c] = v;
        } else {
          int bb = r >> 11, t = r & 2047;
          int sec = c >> 10, cc = c & 1023;
          int hh = cc >> 6, d = cc & 63;
          size_t bh = (size_t)bb * NHEAD + hh;
          if (sec == 0)      q_buf[(bh * TSEQ + (size_t)t) * DH + d] = (__bf16)(v * SCALE2);
          else if (sec == 1) k_buf[(bh * TSEQ + (size_t)t) * DH + d] = (__bf16)v;
          else               vT_buf[(bh * DH + (size_t)d) * TSEQ + t] = (__bf16)v;
        }
      }
    }
  }
}

// ---------------- flash attention: heavy+light pairs, split-K by tile parity --------
// 1 wave/block; wave (bh, wv, hf) handles groups {127-wv, wv}, tiles j = hf, hf+2, ...
// Light tile set nested in heavy set -> shared K/V loads. 4096 uniform waves.
// Writes partials (o bf16, m/l fp32); combine kernel merges the two halves.
// Q pre-scaled; ALiBi row term dropped (softmax-invariant); col bias = 1 fma/n/tile.
template <bool MASK>
__device__ __forceinline__ void qk_softmax_p(
    int kt, int qrow0, int lane, float ktb, const float* pre_n,
    const bf16x8* qf, const bf16x8 (*kf)[2],
    f32x4* o, float* mrow, float* lrow, __bf16 (*p)[68]) {
  f32x4 s[4];
#pragma unroll
  for (int n = 0; n < 4; ++n) {
    f32x4 z = {};
    z = __builtin_amdgcn_mfma_f32_16x16x32_bf16(qf[0], kf[n][0], z, 0, 0, 0);
    s[n] = __builtin_amdgcn_mfma_f32_16x16x32_bf16(qf[1], kf[n][1], z, 0, 0, 0);
  }
  const int qr0 = qrow0 + (lane >> 4) * 4;
  float sv[4][4];
  float tmax[4] = {-__builtin_inff(), -__builtin_inff(), -__builtin_inff(), -__builtin_inff()};
#pragma unroll
  for (int n = 0; n < 4; ++n) {
    const float cb = ktb + pre_n[n];  // slope2 * kc
    const int kc = kt + n * 16 + (lane & 15);
#pragma unroll
    for (int i = 0; i < 4; ++i) {
      float x = s[n][i] + cb;
      if (MASK) x = (kc <= qr0 + i) ? x : -__builtin_inff();
      sv[n][i] = x;
      tmax[i] = fmaxf(tmax[i], x);
    }
  }
#pragma unroll
  for (int i = 0; i < 4; ++i) {
    float t = redmax16(tmax[i]);
    float mnew = fmaxf(mrow[i], t);
    float corr = fexp2(mrow[i] - mnew);
    mrow[i] = mnew;
    float pf[4];
#pragma unroll
    for (int n = 0; n < 4; ++n) pf[n] = fexp2(sv[n][i] - mnew);
    float rs = redsum16((pf[0] + pf[1]) + (pf[2] + pf[3]));
    lrow[i] = lrow[i] * corr + rs;
#pragma unroll
    for (int n2 = 0; n2 < 4; ++n2) o[n2][i] *= corr;
#pragma unroll
    for (int n = 0; n < 4; ++n)
      p[(lane >> 4) * 4 + i][n * 16 + (lane & 15)] = (__bf16)pf[n];
  }
}

__device__ __forceinline__ void pv_acc(
    int lane, const bf16x8 (*vf)[2], f32x4* o, const __bf16 (*p)[68]) {
  bf16x8 pa[2];
#pragma unroll
  for (int kk = 0; kk < 2; ++kk)
    pa[kk] = *(const bf16x8*)&p[lane & 15][kk * 32 + (lane >> 4) * 8];
#pragma unroll
  for (int n2 = 0; n2 < 4; ++n2) {
    o[n2] = __builtin_amdgcn_mfma_f32_16x16x32_bf16(pa[0], vf[n2][0], o[n2], 0, 0, 0);
    o[n2] = __builtin_amdgcn_mfma_f32_16x16x32_bf16(pa[1], vf[n2][1], o[n2], 0, 0, 0);
  }
}

__global__ __launch_bounds__(64) void attn_fwd(
    const __bf16* __restrict__ q_buf, const __bf16* __restrict__ k_buf,
    const __bf16* __restrict__ vT_buf, __bf16* __restrict__ o_part,
    float* __restrict__ ml_part) {
  const int T = TSEQ;
  const int lane = threadIdx.x;
  const int bh = blockIdx.x;
  const int wv = blockIdx.y >> 1;
  const int hf = blockIdx.y & 1;
  const int h = bh & 15;
  const int grp[2] = {127 - wv, wv};  // heavy, light
  const int row0[2] = {grp[0] * 16, grp[1] * 16};
  const int nT[2] = {grp[0] / 4 + 1, grp[1] / 4 + 1};
  const int lastT[2] = {grp[0] / 4, grp[1] / 4};
  const float slope2 = exp2f(-0.5f * (float)(h + 1)) * 1.44269504f;
  const __bf16* qp = q_buf + (size_t)bh * T * DH;
  const __bf16* kp = k_buf + (size_t)bh * T * DH;
  const __bf16* vp = vT_buf + (size_t)bh * DH * T;

  __shared__ alignas(16) __bf16 p_lds[2][16][68];

  bf16x8 qf[2][2];
#pragma unroll
  for (int g = 0; g < 2; ++g) {
    const __bf16* qr = &qp[(size_t)(row0[g] + (lane & 15)) * DH + (lane >> 4) * 8];
    qf[g][0] = *(const bf16x8*)qr;
    qf[g][1] = *(const bf16x8*)(qr + 32);
  }

  f32x4 o[2][4] = {};
  float mrow[2][4], lrow[2][4];
#pragma unroll
  for (int g = 0; g < 2; ++g)
#pragma unroll
    for (int i = 0; i < 4; ++i) { mrow[g][i] = -__builtin_inff(); lrow[g][i] = 0.f; }

  const int klo = (lane & 15) * DH + (lane >> 4) * 8;
  const int vlo = (lane & 15) * T + (lane >> 4) * 8;

  float pre_n[4];
#pragma unroll
  for (int n = 0; n < 4; ++n) pre_n[n] = slope2 * (float)(n * 16 + (lane & 15));

  bf16x8 kf[4][2];
  {
    const int kt0 = hf * 64;
#pragma unroll
    for (int n = 0; n < 4; ++n) {
      const __bf16* kr = kp + (size_t)(kt0 + n * 16) * DH + klo;
      kf[n][0] = *(const bf16x8*)kr;
      kf[n][1] = *(const bf16x8*)(kr + 32);
    }
  }

  for (int j = hf; j < nT[0]; j += 2) {
    const int kt = j * 64;
    bf16x8 vf[4][2];
#pragma unroll
    for (int n2 = 0; n2 < 4; ++n2) {
      const __bf16* vr = vp + vlo + n2 * 16 * T + kt;
      vf[n2][0] = *(const bf16x8*)vr;
      vf[n2][1] = *(const bf16x8*)(vr + 32);
    }
    bf16x8 kn[4][2];
    const bool pre = (j + 2 < nT[0]);
    if (pre) {
#pragma unroll
      for (int n = 0; n < 4; ++n) {
        const __bf16* kr = kp + (size_t)(kt + 128 + n * 16) * DH + klo;
        kn[n][0] = *(const bf16x8*)kr;
        kn[n][1] = *(const bf16x8*)(kr + 32);
      }
    }
    const float ktb = slope2 * (float)kt;
    const bool l_act = (j < nT[1]);
    if (j == lastT[0])
      qk_softmax_p<true>(kt, row0[0], lane, ktb, pre_n, qf[0], kf, o[0], mrow[0], lrow[0], p_lds[0]);
    else
      qk_softmax_p<false>(kt, row0[0], lane, ktb, pre_n, qf[0], kf, o[0], mrow[0], lrow[0], p_lds[0]);
    if (l_act) {
      if (j == lastT[1])
        qk_softmax_p<true>(kt, row0[1], lane, ktb, pre_n, qf[1], kf, o[1], mrow[1], lrow[1], p_lds[1]);
      else
        qk_softmax_p<false>(kt, row0[1], lane, ktb, pre_n, qf[1], kf, o[1], mrow[1], lrow[1], p_lds[1]);
    }
    pv_acc(lane, vf, o[0], p_lds[0]);
    if (l_act) pv_acc(lane, vf, o[1], p_lds[1]);
    if (pre) {
#pragma unroll
      for (int n = 0; n < 4; ++n) {
        kf[n][0] = kn[n][0];
        kf[n][1] = kn[n][1];
      }
    }
  }

  // write partials
  const size_t pbase = (size_t)hf * 4096 + (size_t)bh * 128;
#pragma unroll
  for (int g = 0; g < 2; ++g) {
    const size_t gb = (pbase + grp[g]) * 1024;
#pragma unroll
    for (int i = 0; i < 4; ++i)
#pragma unroll
      for (int n2 = 0; n2 < 4; ++n2)
        o_part[gb + (size_t)(((lane >> 4) * 4 + i) * 64 + n2 * 16 + (lane & 15))] =
            (__bf16)o[g][n2][i];
    if ((lane & 15) == 0) {
      float* mlp = ml_part + (pbase + grp[g]) * 32;
#pragma unroll
      for (int i = 0; i < 4; ++i) {
        mlp[(lane >> 4) * 4 + i] = mrow[g][i];
        mlp[16 + (lane >> 4) * 4 + i] = lrow[g][i];
      }
    }
  }
}

// ---------------- combine the two K-halves ----------------
__global__ __launch_bounds__(256) void attn_combine(
    const __bf16* __restrict__ o_part, const float* __restrict__ ml_part,
    __bf16* __restrict__ y_buf) {
  const int lane = threadIdx.x & 63;          // d
  const int grp = blockIdx.x * 4 + (threadIdx.x >> 6);  // bh*128 + g
  const int bh = grp >> 7, g = grp & 127;
  const int b = bh >> 4, h = bh & 15;
  const float* ml0 = ml_part + (size_t)grp * 32;
  const float* ml1 = ml_part + (size_t)(4096 + grp) * 32;
  const __bf16* op0 = o_part + (size_t)grp * 1024;
  const __bf16* op1 = o_part + (size_t)(4096 + grp) * 1024;
#pragma unroll 4
  for (int r = 0; r < 16; ++r) {
    float m0 = ml0[r], l0 = ml0[16 + r];
    float m1 = ml1[r], l1 = ml1[16 + r];
    float mm = fmaxf(m0, m1);
    float e0 = fexp2(m0 - mm), e1 = fexp2(m1 - mm);
    float inv = 1.0f / (l0 * e0 + l1 * e1);
    float o0 = (float)op0[r * 64 + lane], o1 = (float)op1[r * 64 + lane];
    int t = g * 16 + r;
    y_buf[((size_t)b * TSEQ + t) * CDIM + h * DH + lane] =
        (__bf16)((o0 * e0 + o1 * e1) * inv);
  }
}

extern "C" void kernel_launch(void* const* d_in, const int* in_sizes, int n_in,
                              void* d_out, int out_size, void* d_ws, size_t ws_size,
                              hipStream_t stream) {
  const float* x      = (const float*)d_in[0];
  const float* W_attn = (const float*)d_in[1];
  const float* b_attn = (const float*)d_in[2];
  const float* W_proj = (const float*)d_in[3];
  const float* b_proj = (const float*)d_in[4];
  float* out = (float*)d_out;
  char* ws = (char*)d_ws;
  const size_t MB = (size_t)1 << 20;
  __bf16* xb  = (__bf16*)(ws + 0 * MB);   // dead after qkv gemm; ml_part overlays it
  __bf16* wab = (__bf16*)(ws + 8 * MB);
  __bf16* wpb = (__bf16*)(ws + 14 * MB);
  __bf16* qbf = (__bf16*)(ws + 16 * MB);
  __bf16* kbf = (__bf16*)(ws + 24 * MB);
  __bf16* vtb = (__bf16*)(ws + 32 * MB);
  __bf16* yb  = (__bf16*)(ws + 40 * MB);
  float*  mlp = (float*)(ws + 0 * MB);    // 1 MB, overlays dead xb
  __bf16* opart = (__bf16*)d_out;         // 16 MB scratch; proj overwrites after

  cvt_bf16<<<2048, 256, 0, stream>>>(x, xb, 524288);
  cvt_bf16<<<1536, 256, 0, stream>>>(W_attn, wab, 393216);
  cvt_bf16<<<512, 256, 0, stream>>>(W_proj, wpb, 131072);

  gemm_bt<1><<<dim3(24, 32), 256, 0, stream>>>(xb, wab, b_attn, nullptr,
                                               qbf, kbf, vtb, 4096, 3072, 1024);
  attn_fwd<<<dim3(32, 128), 64, 0, stream>>>(qbf, kbf, vtb, opart, mlp);
  attn_combine<<<1024, 256, 0, stream>>>(opart, mlp, yb);
  gemm_bt<0><<<dim3(8, 32), 256, 0, stream>>>(yb, wpb, b_proj, out,
                                              nullptr, nullptr, nullptr, 4096, 1024, 1024);
}